// Round 1
// baseline (534.496 us; speedup 1.0000x reference)
//
#include <hip/hip_runtime.h>

typedef unsigned long long u64;
typedef unsigned int u32;

#define N_PTS 32768
#define B_SCENES 4
#define M_PTS 8192
#define C_IN 6
#define H_DIM 64
#define KNEAR 16
#define KFAR 32
#define KSM 8

#define QB 32          // queries per block (knn)
#define SEG 8          // candidate segments
#define SEGC (M_PTS/SEG)   // 1024
#define SUBT 128       // per-iteration per-segment subtile
#define NITER (SEGC/SUBT)  // 8
#define CAP 160
#define CAPP 161

// ws layout (bytes):
// 0    : stats1[128]f
// 512  : bn1[128]f   (scale[64], shift[64])
// 1024 : stats2[128]f
// 1536 : bn2[128]f
// 2048 : blockloss[1024*5] double  -> ends 43008
// 43008: S[32768]f                 -> ends 174080
// 174080: C4[32768] float4         -> ends 698368

__device__ __forceinline__ float gelu_exact(float x) {
    return 0.5f * x * (1.0f + erff(x * 0.70710678118654752f));
}
__device__ __forceinline__ float sigmoidf_(float x) {
    return 1.0f / (1.0f + expf(-x));
}

__global__ __launch_bounds__(256) void k_pack(const float* __restrict__ coords,
                                              float4* __restrict__ C4) {
    int n = blockIdx.x * 256 + threadIdx.x;
    float x = coords[n*3], y = coords[n*3+1], z = coords[n*3+2];
    float sq = fmaf(x, x, fmaf(y, y, z*z));
    C4[n] = make_float4(x, y, z, sq);
}

__global__ __launch_bounds__(256) void k_l1stats(const float* __restrict__ feat,
        const float* __restrict__ W1, const float* __restrict__ b1,
        float* __restrict__ stats) {
    __shared__ float sW[C_IN*H_DIM];
    __shared__ float red[2][4][H_DIM];
    int t = threadIdx.x;
    for (int i = t; i < C_IN*H_DIM; i += 256) sW[i] = W1[i];
    __syncthreads();
    int c = t & 63, r = t >> 6;
    float bias = b1[c];
    float s1 = 0.f, s2 = 0.f;
    for (int n = blockIdx.x*4 + r; n < N_PTS; n += 1024) {
        const float* f = feat + n*C_IN;
        float h = bias;
        #pragma unroll
        for (int k = 0; k < C_IN; ++k) h = fmaf(f[k], sW[k*H_DIM + c], h);
        s1 += h; s2 = fmaf(h, h, s2);
    }
    red[0][r][c] = s1; red[1][r][c] = s2;
    __syncthreads();
    if (t < 64) {
        float a = red[0][0][t]+red[0][1][t]+red[0][2][t]+red[0][3][t];
        float b = red[1][0][t]+red[1][1][t]+red[1][2][t]+red[1][3][t];
        atomicAdd(&stats[t], a);
        atomicAdd(&stats[64+t], b);
    }
}

__global__ void k_bnfin(const float* __restrict__ stats, const float* __restrict__ g,
                        const float* __restrict__ be, float* __restrict__ bn) {
    int c = threadIdx.x;
    float mean = stats[c] * (1.0f/N_PTS);
    float var  = stats[64+c] * (1.0f/N_PTS) - mean*mean;
    float sc = g[c] * rsqrtf(var + 1e-5f);
    bn[c] = sc;
    bn[64+c] = be[c] - mean*sc;
}

__global__ __launch_bounds__(256) void k_l2(const float* __restrict__ feat,
        const float* __restrict__ W1, const float* __restrict__ b1,
        const float* __restrict__ bn1, const float* __restrict__ W2,
        const float* __restrict__ b2, float* __restrict__ stats) {
    __shared__ float sW1[C_IN*H_DIM];
    __shared__ float sW2[H_DIM*H_DIM];
    __shared__ float sA[4][H_DIM];
    __shared__ float red[2][4][H_DIM];
    int t = threadIdx.x;
    for (int i = t; i < C_IN*H_DIM; i += 256) sW1[i] = W1[i];
    for (int i = t; i < H_DIM*H_DIM; i += 256) sW2[i] = W2[i];
    __syncthreads();
    int c = t & 63, r = t >> 6;
    float sc1 = bn1[c], sh1 = bn1[64+c];
    float bias1 = b1[c], bias2 = b2[c];
    float s1 = 0.f, s2 = 0.f;
    for (int n0 = blockIdx.x*4; n0 < N_PTS; n0 += 1024) {
        int n = n0 + r;
        const float* f = feat + n*C_IN;
        float h = bias1;
        #pragma unroll
        for (int k = 0; k < C_IN; ++k) h = fmaf(f[k], sW1[k*H_DIM+c], h);
        float a = gelu_exact(fmaf(sc1, h, sh1));
        __syncthreads();
        sA[r][c] = a;
        __syncthreads();
        float h2 = bias2;
        #pragma unroll
        for (int k = 0; k < H_DIM; ++k) h2 = fmaf(sA[r][k], sW2[k*H_DIM+c], h2);
        s1 += h2; s2 = fmaf(h2, h2, s2);
    }
    red[0][r][c] = s1; red[1][r][c] = s2;
    __syncthreads();
    if (t < 64) {
        float a = red[0][0][t]+red[0][1][t]+red[0][2][t]+red[0][3][t];
        float b = red[1][0][t]+red[1][1][t]+red[1][2][t]+red[1][3][t];
        atomicAdd(&stats[t], a);
        atomicAdd(&stats[64+t], b);
    }
}

__global__ __launch_bounds__(256) void k_score(const float* __restrict__ feat,
        const float* __restrict__ W1, const float* __restrict__ b1,
        const float* __restrict__ bn1, const float* __restrict__ W2,
        const float* __restrict__ b2, const float* __restrict__ bn2,
        const float* __restrict__ W3, const float* __restrict__ b3,
        float* __restrict__ S) {
    __shared__ float sW1[C_IN*H_DIM];
    __shared__ float sW2[H_DIM*H_DIM];
    __shared__ float sA[4][H_DIM];
    int t = threadIdx.x;
    for (int i = t; i < C_IN*H_DIM; i += 256) sW1[i] = W1[i];
    for (int i = t; i < H_DIM*H_DIM; i += 256) sW2[i] = W2[i];
    __syncthreads();
    int c = t & 63, r = t >> 6;
    float sc1 = bn1[c], sh1 = bn1[64+c];
    float sc2 = bn2[c], sh2 = bn2[64+c];
    float bias1 = b1[c], bias2 = b2[c], w3 = W3[c], bb = b3[0];
    for (int n0 = blockIdx.x*4; n0 < N_PTS; n0 += 1024) {
        int n = n0 + r;
        const float* f = feat + n*C_IN;
        float h = bias1;
        #pragma unroll
        for (int k = 0; k < C_IN; ++k) h = fmaf(f[k], sW1[k*H_DIM+c], h);
        float a = gelu_exact(fmaf(sc1, h, sh1));
        __syncthreads();
        sA[r][c] = a;
        __syncthreads();
        float h2 = bias2;
        #pragma unroll
        for (int k = 0; k < H_DIM; ++k) h2 = fmaf(sA[r][k], sW2[k*H_DIM+c], h2);
        float a2 = gelu_exact(fmaf(sc2, h2, sh2));
        float v = a2 * w3;
        #pragma unroll
        for (int m = 32; m; m >>= 1) v += __shfl_xor(v, m, 64);
        if (c == 0) S[n] = sigmoidf_(v + bb);
    }
}

__global__ __launch_bounds__(256) void k_knn(const float4* __restrict__ C4,
        const float* __restrict__ S, const float* __restrict__ coords,
        double* __restrict__ blockloss) {
    __shared__ float4 tile[SEG*SUBT];      // 16 KB
    __shared__ u32 cnts[QB][6];
    __shared__ float tauA[QB];
    __shared__ u32 ccount[QB];
    __shared__ u64 buf[QB][CAPP];          // 40.25 KB, padded stride
    __shared__ double lred[4][5];

    int t = threadIdx.x;
    int q = t & (QB-1);
    int seg = t >> 5;
    int scene = blockIdx.x >> 8;           // 256 blocks per scene
    int ib = blockIdx.x & 255;
    int sbase = scene * M_PTS;
    int qg = sbase + ib*QB + q;
    float4 qc = C4[qg];
    float qsq = qc.w;

    float tpr0 = 0.03125f - qsq, tpr1 = 0.0625f - qsq, tpr2 = 0.125f - qsq,
          tpr3 = 0.25f - qsq,    tpr4 = 0.5f - qsq;
    u32 c0=0,c1=0,c2=0,c3=0,c4=0;
    if (t < QB) ccount[t] = 0;

    // ---- phase 1: count under threshold ladder ----
    for (int it = 0; it < NITER; ++it) {
        __syncthreads();
        {
            int chunk = t >> 5, w = t & 31;
            const float4* src = C4 + sbase + chunk*SEGC + it*SUBT;
            #pragma unroll
            for (int k = 0; k < 4; ++k)
                tile[chunk*SUBT + w + k*32] = src[w + k*32];
        }
        __syncthreads();
        const float4* tp = tile + seg*SUBT;
        #pragma unroll 4
        for (int i = 0; i < SUBT; ++i) {
            float4 cc = tp[i];
            float dot = fmaf(qc.x, cc.x, fmaf(qc.y, cc.y, qc.z*cc.z));
            float e2 = fmaf(-2.0f, dot, cc.w);     // d2 - qsq
            c0 += (e2 < tpr0); c1 += (e2 < tpr1); c2 += (e2 < tpr2);
            c3 += (e2 < tpr3); c4 += (e2 < tpr4);
        }
    }
    __syncthreads();
    if (t < QB*6) ((u32*)cnts)[t] = 0;
    __syncthreads();
    atomicAdd(&cnts[q][0], c0); atomicAdd(&cnts[q][1], c1);
    atomicAdd(&cnts[q][2], c2); atomicAdd(&cnts[q][3], c3);
    atomicAdd(&cnts[q][4], c4);
    __syncthreads();
    if (t < QB) {
        float tau = 1e18f;                 // unreachable fallback
        if (cnts[t][4] >= 32) tau = 0.5f;
        if (cnts[t][3] >= 32) tau = 0.25f;
        if (cnts[t][2] >= 32) tau = 0.125f;
        if (cnts[t][1] >= 32) tau = 0.0625f;
        if (cnts[t][0] >= 32) tau = 0.03125f;
        tauA[t] = tau;
    }
    __syncthreads();
    float taup = tauA[q] - qsq;

    // ---- phase 2: collect keys under chosen tau ----
    for (int it = 0; it < NITER; ++it) {
        __syncthreads();
        {
            int chunk = t >> 5, w = t & 31;
            const float4* src = C4 + sbase + chunk*SEGC + it*SUBT;
            #pragma unroll
            for (int k = 0; k < 4; ++k)
                tile[chunk*SUBT + w + k*32] = src[w + k*32];
        }
        __syncthreads();
        const float4* tp = tile + seg*SUBT;
        int lbase = seg*SEGC + it*SUBT;
        for (int i = 0; i < SUBT; ++i) {
            float4 cc = tp[i];
            float dot = fmaf(qc.x, cc.x, fmaf(qc.y, cc.y, qc.z*cc.z));
            float e2 = fmaf(-2.0f, dot, cc.w);
            if (e2 < taup) {
                float d2 = fmaxf(e2 + qsq, 0.0f);
                u64 key = ((u64)__float_as_uint(d2) << 32) | (u32)(lbase + i);
                u32 pos = atomicAdd(&ccount[q], 1u);
                if (pos < CAP) buf[q][pos] = key;
            }
        }
    }
    __syncthreads();

    // ---- phase 3+4: rank-by-counting + fused losses (8 threads / query) ----
    int tq = t >> 3, l8 = t & 7;
    int qg2 = sbase + ib*QB + tq;
    u32 Mq = min(ccount[tq], (u32)CAP);
    float si = S[qg2];
    float qx = coords[qg2*3], qy = coords[qg2*3+1], qz = coords[qg2*3+2];
    double num=0.0, den=0.0, slp=0.0, sln=0.0;
    float smsum = 0.f;
    for (u32 i = l8; i < Mq; i += 8) {
        u64 key = buf[tq][i];
        u32 rank = 0;
        for (u32 j = 0; j < Mq; ++j) rank += (buf[tq][j] < key);
        if (rank < KFAR) {
            int jl = (int)(u32)(key & 0xffffffffu);
            int jg = sbase + jl;
            float sj = S[jg];
            float sd = fabsf(si - sj);
            float sim = 1.0f - sd;
            if (rank < KNEAR) {
                float dx = qx - coords[jg*3];
                float dy = qy - coords[jg*3+1];
                float dz = qz - coords[jg*3+2];
                float d2 = fmaf(dx,dx,fmaf(dy,dy,dz*dz));
                float d = sqrtf(fmaxf(d2, 1e-24f));
                float w = expf(-d * 10.0f);          // exp(-d/T_LOC)
                num += (double)(w * sd * sd);
                den += (double)w;
                slp += (double)logf(sigmoidf_(2.0f*sim) + 1e-8f);
                if (rank < KSM) smsum += sj;
            } else {
                sln += (double)logf(sigmoidf_(-2.0f*sim) + 1e-8f);
            }
        }
    }
    #pragma unroll
    for (int m = 4; m; m >>= 1) smsum += __shfl_xor(smsum, m, 64);
    double sm = 0.0;
    if (l8 == 0) { float dd = si - smsum*(1.0f/8.0f); sm = (double)(dd*dd); }

    double v[5] = {num, den, slp, sln, sm};
    #pragma unroll
    for (int k = 0; k < 5; ++k) {
        for (int m = 32; m; m >>= 1) v[k] += __shfl_xor(v[k], m, 64);
    }
    int wave = t >> 6;
    if ((t & 63) == 0) {
        #pragma unroll
        for (int k = 0; k < 5; ++k) lred[wave][k] = v[k];
    }
    __syncthreads();
    if (t == 0) {
        #pragma unroll
        for (int k = 0; k < 5; ++k)
            blockloss[(size_t)blockIdx.x*5 + k] =
                lred[0][k] + lred[1][k] + lred[2][k] + lred[3][k];
    }
}

__global__ __launch_bounds__(256) void k_final(const double* __restrict__ blockloss,
                                               float* __restrict__ out) {
    __shared__ double red[256][5];
    int t = threadIdx.x;
    double v[5] = {0,0,0,0,0};
    for (int i = t; i < 1024; i += 256) {
        #pragma unroll
        for (int k = 0; k < 5; ++k) v[k] += blockloss[(size_t)i*5 + k];
    }
    #pragma unroll
    for (int k = 0; k < 5; ++k) red[t][k] = v[k];
    __syncthreads();
    for (int s = 128; s; s >>= 1) {
        if (t < s) {
            #pragma unroll
            for (int k = 0; k < 5; ++k) red[t][k] += red[t+s][k];
        }
        __syncthreads();
    }
    if (t == 0) {
        double num = red[0][0], den = red[0][1], slp = red[0][2],
               sln = red[0][3], ssm = red[0][4];
        double loss_loc = num / fmax(den, 1e-8);
        double inv = 1.0 / ((double)N_PTS * (double)KNEAR);
        double loss_con = -(slp * inv) - (sln * inv);
        double loss_sm = ssm / (double)N_PTS;
        out[0] = (float)(loss_loc + 0.5*loss_con + 0.2*loss_sm);
    }
}

extern "C" void kernel_launch(void* const* d_in, const int* in_sizes, int n_in,
                              void* d_out, int out_size, void* d_ws, size_t ws_size,
                              hipStream_t stream) {
    const float* feat   = (const float*)d_in[0];
    const float* coords = (const float*)d_in[1];
    const float* W1 = (const float*)d_in[2];
    const float* b1 = (const float*)d_in[3];
    const float* g1 = (const float*)d_in[4];
    const float* be1= (const float*)d_in[5];
    const float* W2 = (const float*)d_in[6];
    const float* b2 = (const float*)d_in[7];
    const float* g2 = (const float*)d_in[8];
    const float* be2= (const float*)d_in[9];
    const float* W3 = (const float*)d_in[10];
    const float* b3 = (const float*)d_in[11];

    char* ws = (char*)d_ws;
    float* stats1 = (float*)(ws);
    float* bn1    = (float*)(ws + 512);
    float* stats2 = (float*)(ws + 1024);
    float* bn2    = (float*)(ws + 1536);
    double* blockloss = (double*)(ws + 2048);
    float* S      = (float*)(ws + 43008);
    float4* C4    = (float4*)(ws + 174080);

    hipMemsetAsync(d_ws, 0, 2048, stream);   // stats1 + stats2 only

    hipLaunchKernelGGL(k_pack,    dim3(128), dim3(256), 0, stream, coords, C4);
    hipLaunchKernelGGL(k_l1stats, dim3(256), dim3(256), 0, stream, feat, W1, b1, stats1);
    hipLaunchKernelGGL(k_bnfin,   dim3(1),   dim3(64),  0, stream, stats1, g1, be1, bn1);
    hipLaunchKernelGGL(k_l2,      dim3(256), dim3(256), 0, stream, feat, W1, b1, bn1, W2, b2, stats2);
    hipLaunchKernelGGL(k_bnfin,   dim3(1),   dim3(64),  0, stream, stats2, g2, be2, bn2);
    hipLaunchKernelGGL(k_score,   dim3(256), dim3(256), 0, stream,
                       feat, W1, b1, bn1, W2, b2, bn2, W3, b3, S);
    hipLaunchKernelGGL(k_knn,     dim3(1024), dim3(256), 0, stream, C4, S, coords, blockloss);
    hipLaunchKernelGGL(k_final,   dim3(1),   dim3(256), 0, stream, blockloss, (float*)d_out);
}

// Round 2
// 360.457 us; speedup vs baseline: 1.4828x; 1.4828x over previous
//
#include <hip/hip_runtime.h>

typedef unsigned long long u64;
typedef unsigned int u32;
typedef unsigned short u16;

#define N_PTS 32768
#define M_PTS 8192
#define C_IN 6
#define H_DIM 64

#define G 6
#define NCELL 216            // per scene
#define NCELL_T 864          // 4 scenes
#define CW (1.0f/3.0f)

#define QPP 32               // queries per pass
#define TPQ 8                // threads per query (pair phases)
#define CH 512               // chunk capacity (points)
#define CAP 112
#define CAPP 113

// ladder (d^2 thresholds); t0..t2 always <= g^2 (g >= 1/3 - eps)
#define TL0 0.0494f
#define TL1 0.0740f
#define TL2 0.1110f
#define TL3 0.1736f
#define TL4 0.2600f
#define TL5 0.4000f

// ws layout (bytes):
// 0      : stats1[128]f
// 512    : stats2[128]f
// 1024   : gcount[864]u32            -> 4480   (memset 0..4480)
// 4480   : cellstart[865]u32         -> 7940 (pad to 7944)
// 7944   : cellptr[864]u32           -> 11400 (pad to 11408)
// 11408  : blockloss[864*5]double    -> 45968
// 45968  : S[32768]f                 -> 177040
// 177040 : P4s[32768]float4          -> 701328
// 701328 : pcell16[32768]u16         -> 766864
// 766864 : meta16[32768]u16          -> 832400

__device__ __forceinline__ float gelu_exact(float x) {
    return 0.5f * x * (1.0f + erff(x * 0.70710678118654752f));
}
__device__ __forceinline__ float sigmoidf_(float x) {
    return 1.0f / (1.0f + expf(-x));
}

// ---- grid build ----
__global__ __launch_bounds__(256) void k_cellpack(const float* __restrict__ coords,
        u32* __restrict__ gcount, u16* __restrict__ pcell) {
    int n = blockIdx.x * 256 + threadIdx.x;
    float x = coords[n*3], y = coords[n*3+1], z = coords[n*3+2];
    int cx = min(G-1, max(0, (int)floorf((x + 1.0f) * 3.0f)));
    int cy = min(G-1, max(0, (int)floorf((y + 1.0f) * 3.0f)));
    int cz = min(G-1, max(0, (int)floorf((z + 1.0f) * 3.0f)));
    int scene = n >> 13;
    int gcid = scene * NCELL + (cz*G + cy)*G + cx;
    pcell[n] = (u16)gcid;
    atomicAdd(&gcount[gcid], 1u);
}

__global__ __launch_bounds__(256) void k_scan(const u32* __restrict__ gcount,
        u32* __restrict__ cellstart, u32* __restrict__ cellptr) {
    __shared__ u32 sc[256];
    int t = threadIdx.x;
    u32 loc[4]; u32 s = 0;
    #pragma unroll
    for (int j = 0; j < 4; ++j) {
        int idx = t*4 + j;
        loc[j] = (idx < NCELL_T) ? gcount[idx] : 0u;
        s += loc[j];
    }
    sc[t] = s;
    __syncthreads();
    for (int off = 1; off < 256; off <<= 1) {
        u32 v = sc[t];
        if (t >= off) v += sc[t-off];
        __syncthreads();
        sc[t] = v;
        __syncthreads();
    }
    u32 run = sc[t] - s;   // exclusive
    #pragma unroll
    for (int j = 0; j < 4; ++j) {
        int idx = t*4 + j;
        if (idx < NCELL_T) { cellstart[idx] = run; cellptr[idx] = run; }
        run += loc[j];
    }
    if (t == 255) cellstart[NCELL_T] = sc[255];
}

__global__ __launch_bounds__(256) void k_scatter(const float* __restrict__ coords,
        const u16* __restrict__ pcell, u32* __restrict__ cellptr,
        float4* __restrict__ P4s, u16* __restrict__ meta) {
    int n = blockIdx.x * 256 + threadIdx.x;
    float x = coords[n*3], y = coords[n*3+1], z = coords[n*3+2];
    float sq = fmaf(x, x, fmaf(y, y, z*z));
    u32 pos = atomicAdd(&cellptr[pcell[n]], 1u);
    P4s[pos] = make_float4(x, y, z, sq);
    meta[pos] = (u16)(n & (M_PTS-1));
}

// ---- MLP ----
__global__ __launch_bounds__(256) void k_l1stats(const float* __restrict__ feat,
        const float* __restrict__ W1, const float* __restrict__ b1,
        float* __restrict__ stats) {
    __shared__ float sW[C_IN*H_DIM];
    __shared__ float red[2][4][H_DIM];
    int t = threadIdx.x;
    for (int i = t; i < C_IN*H_DIM; i += 256) sW[i] = W1[i];
    __syncthreads();
    int c = t & 63, r = t >> 6;
    float bias = b1[c];
    float s1 = 0.f, s2 = 0.f;
    for (int n = blockIdx.x*4 + r; n < N_PTS; n += 1024) {
        const float* f = feat + n*C_IN;
        float h = bias;
        #pragma unroll
        for (int k = 0; k < C_IN; ++k) h = fmaf(f[k], sW[k*H_DIM + c], h);
        s1 += h; s2 = fmaf(h, h, s2);
    }
    red[0][r][c] = s1; red[1][r][c] = s2;
    __syncthreads();
    if (t < 64) {
        float a = red[0][0][t]+red[0][1][t]+red[0][2][t]+red[0][3][t];
        float b = red[1][0][t]+red[1][1][t]+red[1][2][t]+red[1][3][t];
        atomicAdd(&stats[t], a);
        atomicAdd(&stats[64+t], b);
    }
}

__global__ __launch_bounds__(256) void k_l2(const float* __restrict__ feat,
        const float* __restrict__ W1, const float* __restrict__ b1,
        const float* __restrict__ stats1, const float* __restrict__ g1,
        const float* __restrict__ be1, const float* __restrict__ W2,
        const float* __restrict__ b2, float* __restrict__ stats) {
    __shared__ float sW1[C_IN*H_DIM];
    __shared__ float sW2[H_DIM*H_DIM];
    __shared__ float sA[4][H_DIM];
    __shared__ float red[2][4][H_DIM];
    int t = threadIdx.x;
    for (int i = t; i < C_IN*H_DIM; i += 256) sW1[i] = W1[i];
    for (int i = t; i < H_DIM*H_DIM; i += 256) sW2[i] = W2[i];
    __syncthreads();
    int c = t & 63, r = t >> 6;
    float mean1 = stats1[c] * (1.0f/N_PTS);
    float var1  = stats1[64+c] * (1.0f/N_PTS) - mean1*mean1;
    float sc1 = g1[c] * rsqrtf(var1 + 1e-5f);
    float sh1 = be1[c] - mean1*sc1;
    float bias1 = b1[c], bias2 = b2[c];
    float s1 = 0.f, s2 = 0.f;
    for (int n0 = blockIdx.x*4; n0 < N_PTS; n0 += 1024) {
        int n = n0 + r;
        const float* f = feat + n*C_IN;
        float h = bias1;
        #pragma unroll
        for (int k = 0; k < C_IN; ++k) h = fmaf(f[k], sW1[k*H_DIM+c], h);
        float a = gelu_exact(fmaf(sc1, h, sh1));
        __syncthreads();
        sA[r][c] = a;
        __syncthreads();
        float h2 = bias2;
        #pragma unroll
        for (int k = 0; k < H_DIM; ++k) h2 = fmaf(sA[r][k], sW2[k*H_DIM+c], h2);
        s1 += h2; s2 = fmaf(h2, h2, s2);
    }
    red[0][r][c] = s1; red[1][r][c] = s2;
    __syncthreads();
    if (t < 64) {
        float a = red[0][0][t]+red[0][1][t]+red[0][2][t]+red[0][3][t];
        float b = red[1][0][t]+red[1][1][t]+red[1][2][t]+red[1][3][t];
        atomicAdd(&stats[t], a);
        atomicAdd(&stats[64+t], b);
    }
}

__global__ __launch_bounds__(256) void k_score(const float* __restrict__ feat,
        const float* __restrict__ W1, const float* __restrict__ b1,
        const float* __restrict__ stats1, const float* __restrict__ g1,
        const float* __restrict__ be1, const float* __restrict__ W2,
        const float* __restrict__ b2, const float* __restrict__ stats2,
        const float* __restrict__ g2v, const float* __restrict__ be2,
        const float* __restrict__ W3, const float* __restrict__ b3,
        float* __restrict__ S) {
    __shared__ float sW1[C_IN*H_DIM];
    __shared__ float sW2[H_DIM*H_DIM];
    __shared__ float sA[4][H_DIM];
    int t = threadIdx.x;
    for (int i = t; i < C_IN*H_DIM; i += 256) sW1[i] = W1[i];
    for (int i = t; i < H_DIM*H_DIM; i += 256) sW2[i] = W2[i];
    __syncthreads();
    int c = t & 63, r = t >> 6;
    float mean1 = stats1[c] * (1.0f/N_PTS);
    float var1  = stats1[64+c] * (1.0f/N_PTS) - mean1*mean1;
    float sc1 = g1[c] * rsqrtf(var1 + 1e-5f);
    float sh1 = be1[c] - mean1*sc1;
    float mean2 = stats2[c] * (1.0f/N_PTS);
    float var2  = stats2[64+c] * (1.0f/N_PTS) - mean2*mean2;
    float sc2 = g2v[c] * rsqrtf(var2 + 1e-5f);
    float sh2 = be2[c] - mean2*sc2;
    float bias1 = b1[c], bias2 = b2[c], w3 = W3[c], bb = b3[0];
    for (int n0 = blockIdx.x*4; n0 < N_PTS; n0 += 1024) {
        int n = n0 + r;
        const float* f = feat + n*C_IN;
        float h = bias1;
        #pragma unroll
        for (int k = 0; k < C_IN; ++k) h = fmaf(f[k], sW1[k*H_DIM+c], h);
        float a = gelu_exact(fmaf(sc1, h, sh1));
        __syncthreads();
        sA[r][c] = a;
        __syncthreads();
        float h2 = bias2;
        #pragma unroll
        for (int k = 0; k < H_DIM; ++k) h2 = fmaf(sA[r][k], sW2[k*H_DIM+c], h2);
        float a2 = gelu_exact(fmaf(sc2, h2, sh2));
        float v = a2 * w3;
        #pragma unroll
        for (int m = 32; m; m >>= 1) v += __shfl_xor(v, m, 64);
        if (c == 0) S[n] = sigmoidf_(v + bb);
    }
}

// ---- grid KNN + fused losses: one block per cell ----
__global__ __launch_bounds__(256) void k_knn(const float4* __restrict__ P4s,
        const u16* __restrict__ meta, const u32* __restrict__ cellstart,
        const float* __restrict__ S, double* __restrict__ blockloss) {
    __shared__ float4 tile[CH];          // 8 KB
    __shared__ u16 tmeta[CH];            // 1 KB
    __shared__ u64 buf[QPP][CAPP];       // 28.9 KB
    __shared__ u32 cnts[QPP][6];
    __shared__ float tauA[QPP];
    __shared__ u32 ccount[QPP];
    __shared__ int runb[16], rune[16], nruns_s;
    __shared__ double lred[4][5];

    int t = threadIdx.x;
    int bid = blockIdx.x;
    int scene = bid / NCELL;
    int cid = bid - scene*NCELL;
    int cx = cid % G, cy = (cid / G) % G, cz = cid / (G*G);
    int sbase = scene * M_PTS;

    int cc[3] = {cx, cy, cz};
    bool wall[3]; int W = 0;
    #pragma unroll
    for (int d = 0; d < 3; ++d) { wall[d] = (cc[d] == 0 || cc[d] == G-1); W += wall[d]; }
    int lo[3], hi[3];
    #pragma unroll
    for (int d = 0; d < 3; ++d) {
        if (W >= 2 && !wall[d]) { lo[d] = min(max(cc[d]-2, 0), G-5); hi[d] = lo[d]+4; }
        else                    { lo[d] = min(max(cc[d]-1, 0), G-3); hi[d] = lo[d]+2; }
    }
    float lof[3], hif[3]; bool lw[3], hw[3];
    #pragma unroll
    for (int d = 0; d < 3; ++d) {
        lof[d] = -1.0f + lo[d]*CW; hif[d] = -1.0f + (hi[d]+1)*CW;
        lw[d] = (lo[d] == 0); hw[d] = (hi[d] == G-1);
    }

    if (t == 0) {
        int nr = 0;
        int nx = hi[0]-lo[0]+1;
        for (int z = lo[2]; z <= hi[2]; ++z)
            for (int y = lo[1]; y <= hi[1]; ++y) {
                int bc = scene*NCELL + (z*G + y)*G + lo[0];
                runb[nr] = (int)cellstart[bc];
                rune[nr] = (int)cellstart[bc + nx];
                ++nr;
            }
        nruns_s = nr;
    }
    int gcid = scene*NCELL + cid;
    int qstart = (int)cellstart[gcid];
    int qn = (int)cellstart[gcid+1] - qstart;
    __syncthreads();
    int nruns = nruns_s;

    double anum=0.0, aden=0.0, aslp=0.0, asln=0.0, asm_=0.0;

    for (int p0 = 0; p0 < qn; p0 += QPP) {
        int qpp = min(QPP, qn - p0);
        int q = t & (QPP-1);
        int lane8 = t >> 5;
        bool qact = q < qpp;
        int qi = qact ? q : (qpp-1);
        float4 qc = P4s[qstart + p0 + qi];
        float qsq = qc.w;
        // per-query guaranteed-coverage radius^2
        float qd[3] = {qc.x, qc.y, qc.z};
        float cov = 1e9f;
        #pragma unroll
        for (int d = 0; d < 3; ++d) {
            if (!lw[d]) cov = fminf(cov, qd[d] - lof[d]);
            if (!hw[d]) cov = fminf(cov, hif[d] - qd[d]);
        }
        float g2 = cov*cov;
        float tp0 = TL0-qsq, tp1 = TL1-qsq, tp2 = TL2-qsq,
              tp3 = TL3-qsq, tp4 = TL4-qsq, tp5 = TL5-qsq;
        u32 c0=0,c1=0,c2=0,c3=0,c4=0,c5=0;

        // ---- count stream ----
        for (int r = 0; r < nruns; ++r) {
            for (int off = runb[r]; off < rune[r]; off += CH) {
                int cnum = min(CH, rune[r] - off);
                __syncthreads();
                for (int j = t; j < cnum; j += 256) {
                    tile[j] = P4s[off + j];
                    tmeta[j] = meta[off + j];
                }
                __syncthreads();
                for (int i = lane8; i < cnum; i += TPQ) {
                    float4 p = tile[i];
                    float dot = fmaf(qc.x, p.x, fmaf(qc.y, p.y, qc.z*p.z));
                    float e2 = fmaf(-2.0f, dot, p.w);
                    c0 += (e2 < tp0); c1 += (e2 < tp1); c2 += (e2 < tp2);
                    c3 += (e2 < tp3); c4 += (e2 < tp4); c5 += (e2 < tp5);
                }
            }
        }
        __syncthreads();
        if (t < QPP*6) ((u32*)cnts)[t] = 0;
        if (t < QPP) ccount[t] = 0;
        __syncthreads();
        if (qact) {
            atomicAdd(&cnts[q][0], c0); atomicAdd(&cnts[q][1], c1);
            atomicAdd(&cnts[q][2], c2); atomicAdd(&cnts[q][3], c3);
            atomicAdd(&cnts[q][4], c4); atomicAdd(&cnts[q][5], c5);
        }
        __syncthreads();
        if (t < QPP) {
            // fallback: largest allowed level
            float tau = TL2;
            if (TL3 <= g2) tau = TL3;
            if (TL4 <= g2) tau = TL4;
            if (TL5 <= g2) tau = TL5;
            if      (cnts[t][0] >= 32) tau = TL0;
            else if (cnts[t][1] >= 32) tau = TL1;
            else if (cnts[t][2] >= 32) tau = TL2;
            else if (TL3 <= g2 && cnts[t][3] >= 32) tau = TL3;
            else if (TL4 <= g2 && cnts[t][4] >= 32) tau = TL4;
            else if (TL5 <= g2 && cnts[t][5] >= 32) tau = TL5;
            tauA[t] = tau;
        }
        __syncthreads();
        float taup = tauA[q] - qsq;

        // ---- collect stream ----
        for (int r = 0; r < nruns; ++r) {
            for (int off = runb[r]; off < rune[r]; off += CH) {
                int cnum = min(CH, rune[r] - off);
                __syncthreads();
                for (int j = t; j < cnum; j += 256) {
                    tile[j] = P4s[off + j];
                    tmeta[j] = meta[off + j];
                }
                __syncthreads();
                int lbase = off - sbase;
                for (int i = lane8; i < cnum; i += TPQ) {
                    float4 p = tile[i];
                    float dot = fmaf(qc.x, p.x, fmaf(qc.y, p.y, qc.z*p.z));
                    float e2 = fmaf(-2.0f, dot, p.w);
                    if (qact && e2 < taup) {
                        float d2 = fmaxf(e2 + qsq, 0.0f);
                        u32 lm = (u32)tmeta[i];
                        u64 key = ((u64)__float_as_uint(d2) << 32)
                                | (lm << 13) | (u32)(lbase + i);
                        u32 pos = atomicAdd(&ccount[q], 1u);
                        if (pos < CAP) buf[q][pos] = key;
                    }
                }
            }
        }
        __syncthreads();

        // ---- rank + losses (8 threads / query) ----
        int tq = t >> 3, l8 = t & 7;
        bool ract = tq < qpp;
        int qs = qstart + p0 + (ract ? tq : 0);
        float4 qf = P4s[qs];
        int qg = sbase + (int)meta[qs];
        float si = S[qg];
        u32 Mq = ract ? min(ccount[tq], (u32)CAP) : 0u;
        double num=0.0, den=0.0, slp=0.0, sln=0.0;
        float smsum = 0.f;
        for (u32 i = l8; i < Mq; i += 8) {
            u64 key = buf[tq][i];
            u32 rank = 0;
            for (u32 j = 0; j < Mq; ++j) rank += (buf[tq][j] < key);
            if (rank < 32) {
                u32 jl = (u32)(key & 0x1FFFu);
                u32 jo = (u32)((key >> 13) & 0x1FFFu);
                float sj = S[sbase + (int)jo];
                float4 cj = P4s[sbase + (int)jl];
                float sd = fabsf(si - sj);
                float sim = 1.0f - sd;
                if (rank < 16) {
                    float dx = qf.x-cj.x, dy = qf.y-cj.y, dz = qf.z-cj.z;
                    float d2 = fmaf(dx,dx,fmaf(dy,dy,dz*dz));
                    float d = sqrtf(fmaxf(d2, 1e-24f));
                    float w = expf(-10.0f*d);
                    num += (double)(w*sd*sd);
                    den += (double)w;
                    slp += (double)logf(sigmoidf_(2.0f*sim) + 1e-8f);
                    if (rank < 8) smsum += sj;
                } else {
                    sln += (double)logf(sigmoidf_(-2.0f*sim) + 1e-8f);
                }
            }
        }
        #pragma unroll
        for (int m = 4; m; m >>= 1) smsum += __shfl_xor(smsum, m, 64);
        anum += num; aden += den; aslp += slp; asln += sln;
        if (l8 == 0 && ract) {
            float dd = si - smsum*0.125f;
            asm_ += (double)(dd*dd);
        }
        __syncthreads();
    }

    double v[5] = {anum, aden, aslp, asln, asm_};
    #pragma unroll
    for (int k = 0; k < 5; ++k) {
        for (int m = 32; m; m >>= 1) v[k] += __shfl_xor(v[k], m, 64);
    }
    int wave = t >> 6;
    if ((t & 63) == 0) {
        #pragma unroll
        for (int k = 0; k < 5; ++k) lred[wave][k] = v[k];
    }
    __syncthreads();
    if (t == 0) {
        #pragma unroll
        for (int k = 0; k < 5; ++k)
            blockloss[(size_t)bid*5 + k] =
                lred[0][k] + lred[1][k] + lred[2][k] + lred[3][k];
    }
}

__global__ __launch_bounds__(256) void k_final(const double* __restrict__ blockloss,
                                               float* __restrict__ out) {
    __shared__ double red[256][5];
    int t = threadIdx.x;
    double v[5] = {0,0,0,0,0};
    for (int i = t; i < NCELL_T; i += 256) {
        #pragma unroll
        for (int k = 0; k < 5; ++k) v[k] += blockloss[(size_t)i*5 + k];
    }
    #pragma unroll
    for (int k = 0; k < 5; ++k) red[t][k] = v[k];
    __syncthreads();
    for (int s = 128; s; s >>= 1) {
        if (t < s) {
            #pragma unroll
            for (int k = 0; k < 5; ++k) red[t][k] += red[t+s][k];
        }
        __syncthreads();
    }
    if (t == 0) {
        double num = red[0][0], den = red[0][1], slp = red[0][2],
               sln = red[0][3], ssm = red[0][4];
        double loss_loc = num / fmax(den, 1e-8);
        double inv = 1.0 / ((double)N_PTS * 16.0);
        double loss_con = -(slp * inv) - (sln * inv);
        double loss_sm = ssm / (double)N_PTS;
        out[0] = (float)(loss_loc + 0.5*loss_con + 0.2*loss_sm);
    }
}

extern "C" void kernel_launch(void* const* d_in, const int* in_sizes, int n_in,
                              void* d_out, int out_size, void* d_ws, size_t ws_size,
                              hipStream_t stream) {
    const float* feat   = (const float*)d_in[0];
    const float* coords = (const float*)d_in[1];
    const float* W1 = (const float*)d_in[2];
    const float* b1 = (const float*)d_in[3];
    const float* g1 = (const float*)d_in[4];
    const float* be1= (const float*)d_in[5];
    const float* W2 = (const float*)d_in[6];
    const float* b2 = (const float*)d_in[7];
    const float* g2 = (const float*)d_in[8];
    const float* be2= (const float*)d_in[9];
    const float* W3 = (const float*)d_in[10];
    const float* b3 = (const float*)d_in[11];

    char* ws = (char*)d_ws;
    float* stats1   = (float*)(ws);
    float* stats2   = (float*)(ws + 512);
    u32* gcount     = (u32*)(ws + 1024);
    u32* cellstart  = (u32*)(ws + 4480);
    u32* cellptr    = (u32*)(ws + 7944);
    double* blockloss = (double*)(ws + 11408);
    float* S        = (float*)(ws + 45968);
    float4* P4s     = (float4*)(ws + 177040);
    u16* pcell      = (u16*)(ws + 701328);
    u16* meta       = (u16*)(ws + 766864);

    hipMemsetAsync(d_ws, 0, 4480, stream);   // stats1, stats2, gcount

    hipLaunchKernelGGL(k_cellpack, dim3(128), dim3(256), 0, stream, coords, gcount, pcell);
    hipLaunchKernelGGL(k_scan,     dim3(1),   dim3(256), 0, stream, gcount, cellstart, cellptr);
    hipLaunchKernelGGL(k_scatter,  dim3(128), dim3(256), 0, stream, coords, pcell, cellptr, P4s, meta);
    hipLaunchKernelGGL(k_l1stats,  dim3(256), dim3(256), 0, stream, feat, W1, b1, stats1);
    hipLaunchKernelGGL(k_l2,       dim3(256), dim3(256), 0, stream,
                       feat, W1, b1, stats1, g1, be1, W2, b2, stats2);
    hipLaunchKernelGGL(k_score,    dim3(256), dim3(256), 0, stream,
                       feat, W1, b1, stats1, g1, be1, W2, b2, stats2, g2, be2, W3, b3, S);
    hipLaunchKernelGGL(k_knn,      dim3(NCELL_T), dim3(256), 0, stream,
                       P4s, meta, cellstart, S, blockloss);
    hipLaunchKernelGGL(k_final,    dim3(1),   dim3(256), 0, stream, blockloss, (float*)d_out);
}